// Round 5
// baseline (59.099 us; speedup 1.0000x reference)
//
#include <hip/hip_runtime.h>

// out[p,:] = x[p,:] @ W + b  — the reference's sort/gather/scatter permutation
// cancels exactly. Pure memory-bound elementwise affine.
//
// R1: 3-load batch, cached strided stores: 35.8 us (FETCH 49.5 / WRITE 101 MB).
// R3: nt strided stores: WRITE amplified 134 MB, 48.6 us.
// R4: LDS-staged full-line nt stores: 35.0 us, FETCH unchanged -> nt buys
//     nothing (harness fill kernels flush caches between replays anyway).
// R5 (this): attack memory-level parallelism. Little's law needs ~7 KB of
// reads in flight per CU for 6.3 TB/s; 3 loads/lane gave ~1.5 KB. Batch 12
// float4 loads per thread (192 B/lane in flight), cached stores (L2 merges
// the 48B-stride pattern; WRITE was exactly 101 MB in R1). No LDS/barriers.

typedef float f32x4 __attribute__((ext_vector_type(4)));

__device__ __forceinline__ void affine4(const f32x4 v0, const f32x4 v1, const f32x4 v2,
                                        f32x4& r0, f32x4& r1, f32x4& r2,
                                        float w00, float w01, float w02,
                                        float w10, float w11, float w12,
                                        float w20, float w21, float w22,
                                        float b0, float b1, float b2)
{
    float p0x = v0.x, p0y = v0.y, p0z = v0.z;
    float p1x = v0.w, p1y = v1.x, p1z = v1.y;
    float p2x = v1.z, p2y = v1.w, p2z = v2.x;
    float p3x = v2.y, p3y = v2.z, p3z = v2.w;

    float o0x = fmaf(p0x, w00, fmaf(p0y, w10, fmaf(p0z, w20, b0)));
    float o0y = fmaf(p0x, w01, fmaf(p0y, w11, fmaf(p0z, w21, b1)));
    float o0z = fmaf(p0x, w02, fmaf(p0y, w12, fmaf(p0z, w22, b2)));

    float o1x = fmaf(p1x, w00, fmaf(p1y, w10, fmaf(p1z, w20, b0)));
    float o1y = fmaf(p1x, w01, fmaf(p1y, w11, fmaf(p1z, w21, b1)));
    float o1z = fmaf(p1x, w02, fmaf(p1y, w12, fmaf(p1z, w22, b2)));

    float o2x = fmaf(p2x, w00, fmaf(p2y, w10, fmaf(p2z, w20, b0)));
    float o2y = fmaf(p2x, w01, fmaf(p2y, w11, fmaf(p2z, w21, b1)));
    float o2z = fmaf(p2x, w02, fmaf(p2y, w12, fmaf(p2z, w22, b2)));

    float o3x = fmaf(p3x, w00, fmaf(p3y, w10, fmaf(p3z, w20, b0)));
    float o3y = fmaf(p3x, w01, fmaf(p3y, w11, fmaf(p3z, w21, b1)));
    float o3z = fmaf(p3x, w02, fmaf(p3y, w12, fmaf(p3z, w22, b2)));

    r0 = f32x4{o0x, o0y, o0z, o1x};
    r1 = f32x4{o1y, o1z, o2x, o2y};
    r2 = f32x4{o2z, o3x, o3y, o3z};
}

__global__ __launch_bounds__(256) void affine3_kernel(
    const float* __restrict__ x,
    const float* __restrict__ W,
    const float* __restrict__ bias,
    float* __restrict__ out,
    long long nbatch,       // number of 12-float4 batches (16 points each)
    long long npoints)
{
    const float w00 = W[0], w01 = W[1], w02 = W[2];
    const float w10 = W[3], w11 = W[4], w12 = W[5];
    const float w20 = W[6], w21 = W[7], w22 = W[8];
    const float b0 = bias[0], b1 = bias[1], b2 = bias[2];

    const long long tid    = (long long)blockIdx.x * blockDim.x + threadIdx.x;
    const long long stride = (long long)gridDim.x * blockDim.x;

    const f32x4* __restrict__ xin = reinterpret_cast<const f32x4*>(x);
    f32x4* __restrict__ xout      = reinterpret_cast<f32x4*>(out);

    for (long long q = tid; q < nbatch; q += stride) {
        const long long base = q * 12;

        // Issue all 12 loads first -> 192 B outstanding per lane.
        f32x4 v[12];
        #pragma unroll
        for (int i = 0; i < 12; ++i) v[i] = xin[base + i];

        // Compute + store group-by-group (compiler emits partial vmcnt waits;
        // stores free registers early).
        #pragma unroll
        for (int g = 0; g < 4; ++g) {
            f32x4 r0, r1, r2;
            affine4(v[3*g+0], v[3*g+1], v[3*g+2], r0, r1, r2,
                    w00, w01, w02, w10, w11, w12, w20, w21, w22, b0, b1, b2);
            xout[base + 3*g + 0] = r0;
            xout[base + 3*g + 1] = r1;
            xout[base + 3*g + 2] = r2;
        }
    }

    // Scalar tail (empty for the bench shape: 25165824 floats = 524288 batches).
    const long long donePts = nbatch * 16;
    for (long long p = donePts + tid; p < npoints; p += stride) {
        float px = x[p * 3 + 0], py = x[p * 3 + 1], pz = x[p * 3 + 2];
        out[p * 3 + 0] = fmaf(px, w00, fmaf(py, w10, fmaf(pz, w20, b0)));
        out[p * 3 + 1] = fmaf(px, w01, fmaf(py, w11, fmaf(pz, w21, b1)));
        out[p * 3 + 2] = fmaf(px, w02, fmaf(py, w12, fmaf(pz, w22, b2)));
    }
}

extern "C" void kernel_launch(void* const* d_in, const int* in_sizes, int n_in,
                              void* d_out, int out_size, void* d_ws, size_t ws_size,
                              hipStream_t stream) {
    const float* x    = (const float*)d_in[0];
    const float* W    = (const float*)d_in[1];
    const float* bias = (const float*)d_in[2];
    float* out        = (float*)d_out;

    const long long n       = (long long)in_sizes[0];  // total floats in x
    const long long npoints = n / 3;
    const long long totalF4 = n / 4;
    const long long nbatch  = totalF4 / 12;            // 12 float4 = 16 points

    const int block = 256;
    long long want = (nbatch + block - 1) / block;
    int grid = (int)(want < 2048 ? (want > 0 ? want : 1) : 2048);

    affine3_kernel<<<grid, block, 0, stream>>>(x, W, bias, out, nbatch, npoints);
}

// Round 6
// 34.064 us; speedup vs baseline: 1.7349x; 1.7349x over previous
//
#include <hip/hip_runtime.h>

// out[p,:] = x[p,:] @ W + b  — the reference's sort/gather/scatter permutation
// cancels exactly. Pure memory-bound elementwise affine.
//
// R1: 48B-stride both sides: 35.8 us (FETCH 49.5 / WRITE 101 MB).
// R3: nt + strided stores: WRITE amplified 134 MB, 48.6 us.
// R4: LDS-staged coalesced nt stores, strided loads: 35.0 us.
// R5: 192B-stride thread-contiguous batch: coalescing collapse, 59 us.
// R6 (this): BOTH sides fully coalesced via XOR-swizzled LDS transpose.
// Every global ld/st instruction is 64 lanes x consecutive 16 B = 1 KB,
// full lines. LDS swizzle s^((s>>3)&7) makes the stride-3 float4 access
// conflict-free (3 coprime to 8 -> 8 distinct bank-quads per 8-lane group).

typedef float f32x4 __attribute__((ext_vector_type(4)));

constexpr int TPB = 256;
constexpr int TILE_F4 = TPB * 3;      // 768 float4 = 12 KB = 1024 points

#define SWZ(s) ((s) ^ ((((s) >> 3)) & 7))

__global__ __launch_bounds__(TPB) void affine3_kernel(
    const float* __restrict__ x,
    const float* __restrict__ W,
    const float* __restrict__ bias,
    float* __restrict__ out,
    long long ntiles,
    long long npoints)
{
    __shared__ f32x4 A[TILE_F4];
    __shared__ f32x4 B[TILE_F4];

    const float w00 = W[0], w01 = W[1], w02 = W[2];
    const float w10 = W[3], w11 = W[4], w12 = W[5];
    const float w20 = W[6], w21 = W[7], w22 = W[8];
    const float b0 = bias[0], b1 = bias[1], b2 = bias[2];

    const int t = threadIdx.x;
    const f32x4* __restrict__ xin = reinterpret_cast<const f32x4*>(x);
    f32x4* __restrict__ xout      = reinterpret_cast<f32x4*>(out);

    const long long tile = blockIdx.x;
    if (tile < ntiles) {
        const long long base = tile * TILE_F4;

        // Coalesced loads -> swizzled LDS.
        #pragma unroll
        for (int i = 0; i < 3; ++i) {
            const int s = i * TPB + t;
            A[SWZ(s)] = xin[base + s];
        }
        __syncthreads();

        // Per-thread-contiguous read from LDS (conflict-free via swizzle).
        f32x4 v0 = A[SWZ(3 * t + 0)];
        f32x4 v1 = A[SWZ(3 * t + 1)];
        f32x4 v2 = A[SWZ(3 * t + 2)];

        float p0x = v0.x, p0y = v0.y, p0z = v0.z;
        float p1x = v0.w, p1y = v1.x, p1z = v1.y;
        float p2x = v1.z, p2y = v1.w, p2z = v2.x;
        float p3x = v2.y, p3y = v2.z, p3z = v2.w;

        float o0x = fmaf(p0x, w00, fmaf(p0y, w10, fmaf(p0z, w20, b0)));
        float o0y = fmaf(p0x, w01, fmaf(p0y, w11, fmaf(p0z, w21, b1)));
        float o0z = fmaf(p0x, w02, fmaf(p0y, w12, fmaf(p0z, w22, b2)));

        float o1x = fmaf(p1x, w00, fmaf(p1y, w10, fmaf(p1z, w20, b0)));
        float o1y = fmaf(p1x, w01, fmaf(p1y, w11, fmaf(p1z, w21, b1)));
        float o1z = fmaf(p1x, w02, fmaf(p1y, w12, fmaf(p1z, w22, b2)));

        float o2x = fmaf(p2x, w00, fmaf(p2y, w10, fmaf(p2z, w20, b0)));
        float o2y = fmaf(p2x, w01, fmaf(p2y, w11, fmaf(p2z, w21, b1)));
        float o2z = fmaf(p2x, w02, fmaf(p2y, w12, fmaf(p2z, w22, b2)));

        float o3x = fmaf(p3x, w00, fmaf(p3y, w10, fmaf(p3z, w20, b0)));
        float o3y = fmaf(p3x, w01, fmaf(p3y, w11, fmaf(p3z, w21, b1)));
        float o3z = fmaf(p3x, w02, fmaf(p3y, w12, fmaf(p3z, w22, b2)));

        B[SWZ(3 * t + 0)] = f32x4{o0x, o0y, o0z, o1x};
        B[SWZ(3 * t + 1)] = f32x4{o1y, o1z, o2x, o2y};
        B[SWZ(3 * t + 2)] = f32x4{o2z, o3x, o3y, o3z};
        __syncthreads();

        // Coalesced full-line nt stores.
        #pragma unroll
        for (int i = 0; i < 3; ++i) {
            const int s = i * TPB + t;
            __builtin_nontemporal_store(B[SWZ(s)], &xout[base + s]);
        }
    }

    // Scalar tail (empty for the bench shape: 8192*1024 points exactly).
    const long long donePts = ntiles * 1024;
    const long long gtid    = (long long)blockIdx.x * TPB + t;
    const long long gstride = (long long)gridDim.x * TPB;
    for (long long p = donePts + gtid; p < npoints; p += gstride) {
        float px = x[p * 3 + 0], py = x[p * 3 + 1], pz = x[p * 3 + 2];
        out[p * 3 + 0] = fmaf(px, w00, fmaf(py, w10, fmaf(pz, w20, b0)));
        out[p * 3 + 1] = fmaf(px, w01, fmaf(py, w11, fmaf(pz, w21, b1)));
        out[p * 3 + 2] = fmaf(px, w02, fmaf(py, w12, fmaf(pz, w22, b2)));
    }
}

extern "C" void kernel_launch(void* const* d_in, const int* in_sizes, int n_in,
                              void* d_out, int out_size, void* d_ws, size_t ws_size,
                              hipStream_t stream) {
    const float* x    = (const float*)d_in[0];
    const float* W    = (const float*)d_in[1];
    const float* bias = (const float*)d_in[2];
    float* out        = (float*)d_out;

    const long long n       = (long long)in_sizes[0];  // total floats in x
    const long long npoints = n / 3;
    const long long totalF4 = n / 4;
    const long long ntiles  = totalF4 / TILE_F4;

    long long grid = ntiles > 0 ? ntiles : 1;

    affine3_kernel<<<(int)grid, TPB, 0, stream>>>(x, W, bias, out, ntiles, npoints);
}